// Round 1
// baseline (119.205 us; speedup 1.0000x reference)
//
#include <hip/hip_runtime.h>

#define B_   32
#define ICN  1152
#define OCN  10
#define IDN  8
#define ODN  16
#define NIT  5
#define EPS  1e-20f
#define OUTN (B_ * OCN * ODN)   // 5120

// ---------------------------------------------------------------------------
// Main kernel: one block = one (or K) input capsule(s); 320 threads = 32 b x 10 oc.
// Each thread runs the full 5-iteration NNMF for its (b, ic, oc) with the
// 8x16 weight slice register-resident, then alpha is normalized across oc via
// LDS, and h*alpha_n accumulated over the block's K ics into registers.
// Partial [5120] per block goes to ws (or atomicAdd fallback).
// ---------------------------------------------------------------------------
template <int K>
__global__ __launch_bounds__(320, 2) void caps_main(
    const float* __restrict__ xg, const float* __restrict__ wg,
    float* __restrict__ ws, float* __restrict__ outg, int atomic_out) {
  // padded: each oc chunk is 132 floats (128 + 4) -> stride 528B = 33*16B,
  // keeps float4 alignment and breaks the oc*512B same-bank collision.
  __shared__ float sw[OCN * 132];
  __shared__ float s_alpha[320];

  const int t = threadIdx.x;          // 0..319
  const int b = t / OCN;              // 0..31
  const int oc = t % OCN;             // 0..9

  float acc[ODN];
#pragma unroll
  for (int d = 0; d < ODN; ++d) acc[d] = 0.f;

  for (int icl = 0; icl < K; ++icl) {
    const int ic = blockIdx.x * K + icl;

    __syncthreads();  // protect sw/s_alpha from previous iteration's readers
    {
      // stage w[ic][*][*][*] = 1280 floats = 320 float4, one per thread
      const float4 v = ((const float4*)(wg + (size_t)ic * (OCN * IDN * ODN)))[t];
      const int oc_s = t >> 5;   // float4 index t -> oc chunk t*4/128
      const int rem = t & 31;    // float4 within chunk
      *(float4*)(sw + oc_s * 132 + rem * 4) = v;
    }
    __syncthreads();

    // copy my oc's 8x16 slice into registers (<=2-way LDS bank aliasing: free)
    float wr[IDN][ODN];
#pragma unroll
    for (int q = 0; q < 32; ++q) {
      const float4 v = *(const float4*)(sw + oc * 132 + q * 4);
      const int id = q >> 2;
      const int o0 = (q & 3) * 4;
      wr[id][o0 + 0] = v.x; wr[id][o0 + 1] = v.y;
      wr[id][o0 + 2] = v.z; wr[id][o0 + 3] = v.w;
    }

    // load x[b, ic, :] and normalize over id
    float xn[IDN];
    {
      const float* xp = xg + ((size_t)b * ICN + ic) * IDN;
      const float4 a0 = ((const float4*)xp)[0];
      const float4 a1 = ((const float4*)xp)[1];
      xn[0] = a0.x; xn[1] = a0.y; xn[2] = a0.z; xn[3] = a0.w;
      xn[4] = a1.x; xn[5] = a1.y; xn[6] = a1.z; xn[7] = a1.w;
      float s = 0.f;
#pragma unroll
      for (int i = 0; i < IDN; ++i) s += xn[i];
      const float r = __builtin_amdgcn_rcpf(s + EPS);
#pragma unroll
      for (int i = 0; i < IDN; ++i) xn[i] *= r;
    }

    // NNMF-SbS iterations, h register-resident
    float h[ODN];
#pragma unroll
    for (int d = 0; d < ODN; ++d) h[d] = 1.0f / ODN;

    for (int it = 0; it < NIT; ++it) {
      float hacc[ODN];
#pragma unroll
      for (int d = 0; d < ODN; ++d) hacc[d] = 0.f;
#pragma unroll
      for (int id = 0; id < IDN; ++id) {
        float den = 0.f;
#pragma unroll
        for (int d = 0; d < ODN; ++d) den += h[d] * wr[id][d];
        const float tc = xn[id] * __builtin_amdgcn_rcpf(den + EPS);
#pragma unroll
        for (int d = 0; d < ODN; ++d) hacc[d] += wr[id][d] * tc;
      }
      float s = 0.f;
#pragma unroll
      for (int d = 0; d < ODN; ++d) { h[d] *= hacc[d]; s += h[d]; }
      const float r = __builtin_amdgcn_rcpf(s + EPS);
#pragma unroll
      for (int d = 0; d < ODN; ++d) h[d] *= r;
    }

    // alpha = sum_id (sum_od h*w) * xn
    float a = 0.f;
#pragma unroll
    for (int id = 0; id < IDN; ++id) {
      float rec = 0.f;
#pragma unroll
      for (int d = 0; d < ODN; ++d) rec += h[d] * wr[id][d];
      a += rec * xn[id];
    }
    s_alpha[t] = a;
    __syncthreads();
    float asum = 0.f;
#pragma unroll
    for (int k2 = 0; k2 < OCN; ++k2) asum += s_alpha[b * OCN + k2];
    const float an = a * __builtin_amdgcn_rcpf(asum + EPS);
#pragma unroll
    for (int d = 0; d < ODN; ++d) acc[d] += h[d] * an;
  }

  if (!atomic_out) {
    float* dst = ws + (size_t)blockIdx.x * OUTN + t * ODN;  // coalesced
#pragma unroll
    for (int q = 0; q < 4; ++q) {
      float4 v;
      v.x = acc[q * 4 + 0]; v.y = acc[q * 4 + 1];
      v.z = acc[q * 4 + 2]; v.w = acc[q * 4 + 3];
      ((float4*)dst)[q] = v;
    }
  } else {
#pragma unroll
    for (int d = 0; d < ODN; ++d) atomicAdd(outg + t * ODN + d, acc[d]);
  }
}

// ---------------------------------------------------------------------------
// Reduce: out[j] += sum over this group's rows of ws[row][j].
// grid = (5120/64, 8); 8 atomic contenders per address (out pre-zeroed).
// ---------------------------------------------------------------------------
template <int RPG>
__global__ void caps_reduce(const float* __restrict__ ws, float* __restrict__ outg) {
  const int j = blockIdx.x * 64 + threadIdx.x;
  const int r0 = blockIdx.y * RPG;
  float s = 0.f;
#pragma unroll 4
  for (int r = 0; r < RPG; ++r) s += ws[(size_t)(r0 + r) * OUTN + j];
  atomicAdd(outg + j, s);
}

extern "C" void kernel_launch(void* const* d_in, const int* in_sizes, int n_in,
                              void* d_out, int out_size, void* d_ws, size_t ws_size,
                              hipStream_t stream) {
  const float* x = (const float*)d_in[0];
  const float* w = (const float*)d_in[1];
  float* out = (float*)d_out;
  float* ws = (float*)d_ws;

  hipMemsetAsync(out, 0, OUTN * sizeof(float), stream);

  const size_t need1 = (size_t)(ICN / 1) * OUTN * sizeof(float);  // 23.6 MB
  const size_t need4 = (size_t)(ICN / 4) * OUTN * sizeof(float);  //  5.9 MB

  if (ws_size >= need1) {
    caps_main<1><<<ICN / 1, 320, 0, stream>>>(x, w, ws, out, 0);
    caps_reduce<(ICN / 1) / 8><<<dim3(OUTN / 64, 8), 64, 0, stream>>>(ws, out);
  } else if (ws_size >= need4) {
    caps_main<4><<<ICN / 4, 320, 0, stream>>>(x, w, ws, out, 0);
    caps_reduce<(ICN / 4) / 8><<<dim3(OUTN / 64, 8), 64, 0, stream>>>(ws, out);
  } else {
    caps_main<4><<<ICN / 4, 320, 0, stream>>>(x, w, nullptr, out, 1);
  }
}

// Round 2
// 90.867 us; speedup vs baseline: 1.3119x; 1.3119x over previous
//
#include <hip/hip_runtime.h>

#define B_   32
#define ICN  1152
#define OCN  10
#define IDN  8
#define ODN  16
#define ODH  8                  // od half width (split across 2 lanes)
#define NIT  5
#define EPS  1e-20f
#define OUTN (B_ * OCN * ODN)   // 5120
#define BGRP 11                 // ceil(32 b / 3 groups per wave)
#define NBLK (BGRP * ICN)       // 12672 one-wave blocks

// ---------------------------------------------------------------------------
// One wave (64 lanes) = 3 (b,ic) groups of 20 lanes (10 oc x 2 od-halves),
// lanes 60..63 idle. Each lane keeps its 8x8 weight slice in REGISTERS
// (64 VGPRs), runs 5 NNMF iterations with cross-half reductions via
// shfl_xor(1), alpha normalized over oc via 10 in-wave shuffles.
// No LDS, no barriers. Partial [5120] per ic goes to ws; reduce kernel sums.
// ---------------------------------------------------------------------------
__global__ __launch_bounds__(64, 4) void caps_main(
    const float* __restrict__ xg, const float* __restrict__ wg,
    float* __restrict__ ws, float* __restrict__ outg, int atomic_out) {
  const int l = threadIdx.x;
  const int bid = blockIdx.x;
  const int ic = bid % ICN;      // same-ic blocks 1152 apart -> same XCD (1152%8==0)
  const int bgrp = bid / ICN;    // 0..10
  const int grp = l / 20;        // 0..3 (3 = idle lanes 60..63)
  const int q = l % 20;
  const int oc = q >> 1;         // 0..9
  const int half = q & 1;        // 0,1
  const int b = bgrp * 3 + grp;
  const bool valid = (grp < 3) && (b < B_);
  const int bb = (b < B_) ? b : (B_ - 1);   // clamp for loads only

  // ---- weights slice -> registers: w[ic][oc][id][half*8 .. +8) ----
  float wr[IDN][ODH];
  {
    const float* wp = wg + ((size_t)ic * OCN + oc) * (IDN * ODN) + half * ODH;
#pragma unroll
    for (int id = 0; id < IDN; ++id) {
      const float4 v0 = *(const float4*)(wp + id * ODN);
      const float4 v1 = *(const float4*)(wp + id * ODN + 4);
      wr[id][0] = v0.x; wr[id][1] = v0.y; wr[id][2] = v0.z; wr[id][3] = v0.w;
      wr[id][4] = v1.x; wr[id][5] = v1.y; wr[id][6] = v1.z; wr[id][7] = v1.w;
    }
  }

  // ---- x[b,ic,:] normalized over id ----
  float xn[IDN];
  {
    const float* xp = xg + ((size_t)bb * ICN + ic) * IDN;
    const float4 a0 = ((const float4*)xp)[0];
    const float4 a1 = ((const float4*)xp)[1];
    xn[0] = a0.x; xn[1] = a0.y; xn[2] = a0.z; xn[3] = a0.w;
    xn[4] = a1.x; xn[5] = a1.y; xn[6] = a1.z; xn[7] = a1.w;
    float s = 0.f;
#pragma unroll
    for (int i = 0; i < IDN; ++i) s += xn[i];
    const float r = __builtin_amdgcn_rcpf(s + EPS);
#pragma unroll
    for (int i = 0; i < IDN; ++i) xn[i] *= r;
  }

  // ---- NNMF iterations ----
  float h[ODH];
#pragma unroll
  for (int k = 0; k < ODH; ++k) h[k] = 1.0f / ODN;

  for (int it = 0; it < NIT; ++it) {
    float hacc[ODH];
#pragma unroll
    for (int k = 0; k < ODH; ++k) hacc[k] = 0.f;
#pragma unroll
    for (int id = 0; id < IDN; ++id) {
      float pd = 0.f;
#pragma unroll
      for (int k = 0; k < ODH; ++k) pd = fmaf(h[k], wr[id][k], pd);
      const float den = pd + __shfl_xor(pd, 1, 64);   // full 16-od sum
      const float tc = xn[id] * __builtin_amdgcn_rcpf(den + EPS);
#pragma unroll
      for (int k = 0; k < ODH; ++k) hacc[k] = fmaf(wr[id][k], tc, hacc[k]);
    }
    float ps = 0.f;
#pragma unroll
    for (int k = 0; k < ODH; ++k) { h[k] *= hacc[k]; ps += h[k]; }
    const float hs = ps + __shfl_xor(ps, 1, 64);      // full 16-od sum
    const float r = __builtin_amdgcn_rcpf(hs + EPS);
#pragma unroll
    for (int k = 0; k < ODH; ++k) h[k] *= r;
  }

  // ---- alpha = sum_id (sum_od h*w) * xn, normalized over oc ----
  float ap = 0.f;
#pragma unroll
  for (int id = 0; id < IDN; ++id) {
    float rec = 0.f;
#pragma unroll
    for (int k = 0; k < ODH; ++k) rec = fmaf(h[k], wr[id][k], rec);
    ap = fmaf(rec, xn[id], ap);
  }
  const float af = ap + __shfl_xor(ap, 1, 64);        // full alpha(b,ic,oc)
  float asum = 0.f;
  const int gbase = grp * 20;
#pragma unroll
  for (int k = 0; k < OCN; ++k) asum += __shfl(af, gbase + 2 * k, 64);
  const float an = af * __builtin_amdgcn_rcpf(asum + EPS);

  float o[ODH];
#pragma unroll
  for (int k = 0; k < ODH; ++k) o[k] = h[k] * an;

  if (valid) {
    if (!atomic_out) {
      float* dst = ws + (size_t)ic * OUTN + (bb * OCN + oc) * ODN + half * ODH;
      float4 v0, v1;
      v0.x = o[0]; v0.y = o[1]; v0.z = o[2]; v0.w = o[3];
      v1.x = o[4]; v1.y = o[5]; v1.z = o[6]; v1.w = o[7];
      ((float4*)dst)[0] = v0;
      ((float4*)dst)[1] = v1;
    } else {
      const int base = (bb * OCN + oc) * ODN + half * ODH;
#pragma unroll
      for (int k = 0; k < ODH; ++k) atomicAdd(outg + base + k, o[k]);
    }
  }
}

// ---------------------------------------------------------------------------
// Reduce: out[j] += sum_{r in my 36 rows} ws[r][j].
// grid = (5120/256, 32), block 256 -> 640 blocks / 2560 waves, 36 independent
// loads each (MLP), 32 atomic contenders per address (out pre-zeroed).
// ---------------------------------------------------------------------------
#define RSPLIT 32
#define RROWS  (ICN / RSPLIT)   // 36
__global__ void caps_reduce(const float* __restrict__ ws, float* __restrict__ outg) {
  const int j = blockIdx.x * 256 + threadIdx.x;
  const int r0 = blockIdx.y * RROWS;
  float s = 0.f;
#pragma unroll
  for (int r = 0; r < RROWS; ++r) s += ws[(size_t)(r0 + r) * OUTN + j];
  atomicAdd(outg + j, s);
}

extern "C" void kernel_launch(void* const* d_in, const int* in_sizes, int n_in,
                              void* d_out, int out_size, void* d_ws, size_t ws_size,
                              hipStream_t stream) {
  const float* x = (const float*)d_in[0];
  const float* w = (const float*)d_in[1];
  float* out = (float*)d_out;
  float* ws = (float*)d_ws;

  hipMemsetAsync(out, 0, OUTN * sizeof(float), stream);

  const size_t need = (size_t)ICN * OUTN * sizeof(float);  // 23.6 MB

  if (ws_size >= need) {
    caps_main<<<NBLK, 64, 0, stream>>>(x, w, ws, out, 0);
    caps_reduce<<<dim3(OUTN / 256, RSPLIT), 256, 0, stream>>>(ws, out);
  } else {
    caps_main<<<NBLK, 64, 0, stream>>>(x, w, nullptr, out, 1);
  }
}